// Round 15
// baseline (113.601 us; speedup 1.0000x reference)
//
#include <hip/hip_runtime.h>
#include <cfloat>
#include <math.h>

// Problem constants (fixed by the reference)
#define B_ROWS   4096
#define DIM      512
#define NPROTO   1000
#define NCLASSES 10000
#define KSEL     10
#define KCAND    12                // approx candidates rescored in f32
#define CAP      256               // bucket capacity (avg 41)
#define PROB_LD  1024

// d_out[0, 8MB) holds the f16 prob scratch between k_gemm and k_select.
// k_out later overwrites ALL of d_out with the final dense rows (zeros +
// values fused in one streaming pass -- no separate zeroing anywhere).
#define PROB_BYTES 8388608u

// MFMA GEMM tiling (R10-verified structure)
#define GBM 64
#define GBN 128
#define GBK 32
#define ALD 40                     // padded LDS row stride (bf16 elems)

typedef short s16x8 __attribute__((ext_vector_type(8)));
typedef float f32x4 __attribute__((ext_vector_type(4)));

static __device__ __forceinline__ unsigned short f2bf(float f) {
  unsigned int x = __float_as_uint(f);
  return (unsigned short)((x + 0x7fffu + ((x >> 16) & 1u)) >> 16);  // RNE
}
static __device__ __forceinline__ s16x8 cvt8(float4 a, float4 b) {
  s16x8 r;
  r[0]=f2bf(a.x); r[1]=f2bf(a.y); r[2]=f2bf(a.z); r[3]=f2bf(a.w);
  r[4]=f2bf(b.x); r[5]=f2bf(b.y); r[6]=f2bf(b.z); r[7]=f2bf(b.w);
  return r;
}
static __device__ __forceinline__ unsigned short f2h(float f) {
  _Float16 h = (_Float16)f;
  return __builtin_bit_cast(unsigned short, h);
}
// monotone map: IEEE f16 bits -> u16 preserving order (no NaNs here)
static __device__ __forceinline__ unsigned mono16(unsigned h) {
  return (h & 0x8000u) ? (~h & 0xffffu) : (h | 0x8000u);
}

// ---------------------------------------------------------------------------
// Kernel 1: prob(f16) = bf16(img) @ bf16(proto).T via 16x16x32 MFMA,
// f32->bf16 inline at the LDS-store site (R10-verbatim, no zero work).
// Block (0,0) zeroes counts.
// ---------------------------------------------------------------------------
__global__ __launch_bounds__(256) void k_gemm(
    const float* __restrict__ img, const float* __restrict__ proto,
    unsigned short* __restrict__ prob, int* __restrict__ counts)
{
  __shared__ short Al[GBM * ALD];   // 5 KB
  __shared__ short Bl[GBN * ALD];   // 10 KB

  const int tid  = threadIdx.x;
  const int lane = tid & 63, wave = tid >> 6;
  const int wr = wave >> 1, wc = wave & 1;
  const int row0 = blockIdx.x * GBM;
  const int col0 = blockIdx.y * GBN;

  const int sr = tid >> 2;          // staging row 0..63
  const int sc = (tid & 3) * 8;     // staging k-col 0,8,16,24

  int pa = col0 + sr;      if (pa > NPROTO - 1) pa = NPROTO - 1;
  int pb = col0 + 64 + sr; if (pb > NPROTO - 1) pb = NPROTO - 1;
  const float* gA  = img   + (size_t)(row0 + sr) * DIM + sc;
  const float* gB0 = proto + (size_t)pa * DIM + sc;
  const float* gB1 = proto + (size_t)pb * DIM + sc;

  float4 ra0  = *(const float4*)(gA);      float4 ra1  = *(const float4*)(gA + 4);
  float4 rb00 = *(const float4*)(gB0);     float4 rb01 = *(const float4*)(gB0 + 4);
  float4 rb10 = *(const float4*)(gB1);     float4 rb11 = *(const float4*)(gB1 + 4);

  f32x4 acc[2][4];
#pragma unroll
  for (int m = 0; m < 2; ++m)
#pragma unroll
    for (int n = 0; n < 4; ++n) acc[m][n] = (f32x4)0.f;

  const int kg = lane >> 4;   // k-group 0..3
  const int fr = lane & 15;   // fragment row/col

  for (int kt = 0; kt < DIM / GBK; ++kt) {
    *(s16x8*)&Al[sr * ALD + sc]        = cvt8(ra0, ra1);
    *(s16x8*)&Bl[sr * ALD + sc]        = cvt8(rb00, rb01);
    *(s16x8*)&Bl[(64 + sr) * ALD + sc] = cvt8(rb10, rb11);
    __syncthreads();

    if (kt + 1 < DIM / GBK) {
      const int k0 = (kt + 1) * GBK;
      ra0  = *(const float4*)(gA + k0);   ra1  = *(const float4*)(gA + k0 + 4);
      rb00 = *(const float4*)(gB0 + k0);  rb01 = *(const float4*)(gB0 + k0 + 4);
      rb10 = *(const float4*)(gB1 + k0);  rb11 = *(const float4*)(gB1 + k0 + 4);
    }

    s16x8 af[2], bf[4];
#pragma unroll
    for (int m = 0; m < 2; ++m)
      af[m] = *(const s16x8*)&Al[(wr * 32 + m * 16 + fr) * ALD + kg * 8];
#pragma unroll
    for (int n = 0; n < 4; ++n)
      bf[n] = *(const s16x8*)&Bl[(wc * 64 + n * 16 + fr) * ALD + kg * 8];
#pragma unroll
    for (int m = 0; m < 2; ++m)
#pragma unroll
      for (int n = 0; n < 4; ++n)
        acc[m][n] = __builtin_amdgcn_mfma_f32_16x16x32_bf16(
            af[m], bf[n], acc[m][n], 0, 0, 0);
    __syncthreads();
  }

  // epilogue: C/D layout (m89/m91): col = lane&15, row = (lane>>4)*4 + reg
#pragma unroll
  for (int m = 0; m < 2; ++m)
#pragma unroll
    for (int n = 0; n < 4; ++n) {
      const int r = row0 + wr * 32 + m * 16 + (lane >> 4) * 4;
      const int c = col0 + wc * 64 + n * 16 + fr;
#pragma unroll
      for (int reg = 0; reg < 4; ++reg)
        prob[(size_t)(r + reg) * PROB_LD + c] = f2h(acc[m][n][reg]);
    }

  if (blockIdx.x == 0 && blockIdx.y == 0)
    for (int i = tid; i < NPROTO; i += 256) counts[i] = 0;
}

// ---------------------------------------------------------------------------
// Kernel 2: fused top-12 -> f32 rescore -> top-10 pick -> bucket build.
// One wave per row, register-packed argmax (R10-verbatim). Lane kk also
// records topk[row][kk]; bucket entries encode (row<<4)|slot so the value's
// final position is deterministic regardless of atomic arrival order.
// ---------------------------------------------------------------------------
__global__ __launch_bounds__(256) void k_select(
    const unsigned short* __restrict__ prob, const float* __restrict__ img,
    const float* __restrict__ proto, int* __restrict__ counts,
    int* __restrict__ buckets, int* __restrict__ topk)
{
  const int tid  = threadIdx.x;
  const int wave = tid >> 6, lane = tid & 63;
  const int row  = blockIdx.x * 4 + wave;

  // lane l owns u32 words l*8 .. l*8+7 of the row = cols l*16 .. l*16+15
  unsigned cand[16];
  {
    const uint4* pu = reinterpret_cast<const uint4*>(
        prob + (size_t)row * PROB_LD) + lane * 2;
    const uint4 w0 = pu[0], w1 = pu[1];
    const unsigned w[8] = {w0.x, w0.y, w0.z, w0.w, w1.x, w1.y, w1.z, w1.w};
    const int cbase = lane * 16;
#pragma unroll
    for (int r = 0; r < 8; ++r) {
      const int c0 = cbase + r * 2;
      const unsigned lo = w[r] & 0xffffu, hi = w[r] >> 16;
      cand[r * 2]     = (c0     < NPROTO) ? ((mono16(lo) << 16) | (0xffffu - c0))       : 0u;
      cand[r * 2 + 1] = (c0 + 1 < NPROTO) ? ((mono16(hi) << 16) | (0xffffu - (c0 + 1))) : 0u;
    }
  }

  // 12 rounds of pure-VALU wave argmax
  int ci[KCAND];
#pragma unroll
  for (int kk = 0; kk < KCAND; ++kk) {
    unsigned best = cand[0];
#pragma unroll
    for (int r = 1; r < 16; ++r) best = max(best, cand[r]);
#pragma unroll
    for (int off = 32; off; off >>= 1)
      best = max(best, (unsigned)__shfl_xor((int)best, off));
    ci[kk] = 0xffff - (int)(best & 0xffffu);
#pragma unroll
    for (int r = 0; r < 16; ++r)
      if (cand[r] == best) cand[r] = 0u;
  }

  // exact f32 rescore of the 12 candidates
  const float4* a4 = reinterpret_cast<const float4*>(img + (size_t)row * DIM);
  const float4 a0 = a4[lane], a1 = a4[64 + lane];
  float dv[KCAND];
#pragma unroll
  for (int j = 0; j < KCAND; ++j) {
    const float4* p4 = reinterpret_cast<const float4*>(proto + (size_t)ci[j] * DIM);
    const float4 b0 = p4[lane], b1 = p4[64 + lane];
    float s = 0.f;
    s = fmaf(a0.x, b0.x, s); s = fmaf(a0.y, b0.y, s);
    s = fmaf(a0.z, b0.z, s); s = fmaf(a0.w, b0.w, s);
    s = fmaf(a1.x, b1.x, s); s = fmaf(a1.y, b1.y, s);
    s = fmaf(a1.z, b1.z, s); s = fmaf(a1.w, b1.w, s);
#pragma unroll
    for (int off = 32; off; off >>= 1) s += __shfl_xor(s, off);
    dv[j] = s;
  }

  // top-10 pick + per-slot bucket build + topk record
  unsigned picked = 0;
  for (int kk = 0; kk < KSEL; ++kk) {
    float bv = -FLT_MAX;
    int   bj = 0;
#pragma unroll
    for (int j = 0; j < KCAND; ++j)
      if (!((picked >> j) & 1u) && dv[j] > bv) { bv = dv[j]; bj = j; }
    picked |= 1u << bj;
    if (lane == kk) {
      const int pp  = ci[bj];
      topk[(size_t)row * KSEL + kk] = pp;
      const int pos = atomicAdd(&counts[pp], 1);
      if (pos < CAP) buckets[pp * CAP + pos] = (row << 4) | kk;
    }
  }
}

// ---------------------------------------------------------------------------
// Kernel 3: one block per proto; stage its 10 raw text rows in LDS + inverse
// norms (scale folded into dot epilogue); prefetched bucketed-row loop.
// Writes COMPACT vals[row][slot*10+j] (no d_out scatter).
// ---------------------------------------------------------------------------
__global__ __launch_bounds__(256) void k_compute(
    const float* __restrict__ img, const float* __restrict__ text,
    const int* __restrict__ counts, const int* __restrict__ buckets,
    const float* __restrict__ logit_scale, float* __restrict__ vals)
{
  __shared__ float stext[KSEL * DIM];   // 20 KB (raw)
  __shared__ float sfac[KSEL];

  const int p    = blockIdx.x;
  const int tid  = threadIdx.x;
  const int wave = tid >> 6, lane = tid & 63;

  {
    const float4* src = reinterpret_cast<const float4*>(text + (size_t)p * KSEL * DIM);
    float4* dst = reinterpret_cast<float4*>(stext);
#pragma unroll
    for (int i = 0; i < 5; ++i) dst[tid + i * 256] = src[tid + i * 256];
  }
  __syncthreads();

  const float scale = expf(logit_scale[0]);
#pragma unroll
  for (int j = wave; j < KSEL; j += 4) {
    const float4* t4 = reinterpret_cast<const float4*>(stext + j * DIM);
    float4 v0 = t4[lane], v1 = t4[64 + lane];
    float s = 0.f;
    s = fmaf(v0.x, v0.x, s); s = fmaf(v0.y, v0.y, s);
    s = fmaf(v0.z, v0.z, s); s = fmaf(v0.w, v0.w, s);
    s = fmaf(v1.x, v1.x, s); s = fmaf(v1.y, v1.y, s);
    s = fmaf(v1.z, v1.z, s); s = fmaf(v1.w, v1.w, s);
#pragma unroll
    for (int off = 32; off; off >>= 1) s += __shfl_down(s, off);
    if (lane == 0) sfac[j] = scale / sqrtf(s);
  }
  __syncthreads();

  const int n = min(counts[p], CAP);
  const float4* st4 = reinterpret_cast<const float4*>(stext);
  const int* bkt = buckets + p * CAP;

  int ent = 0, nent;
  float4 a0, a1, na0, na1;
  if (wave < n) {
    ent = bkt[wave];
    const float4* a4 = reinterpret_cast<const float4*>(img + (size_t)(ent >> 4) * DIM);
    a0 = a4[lane]; a1 = a4[64 + lane];
  }

  for (int i = wave; i < n; i += 4) {
    const int inext = i + 4;
    if (inext < n) {
      nent = bkt[inext];
      const float4* a4 = reinterpret_cast<const float4*>(img + (size_t)(nent >> 4) * DIM);
      na0 = a4[lane]; na1 = a4[64 + lane];
    }

    float acc[KSEL];
#pragma unroll
    for (int j = 0; j < KSEL; ++j) {
      const float4 b0 = st4[j * 128 + lane];
      const float4 b1 = st4[j * 128 + 64 + lane];
      float s = 0.f;
      s = fmaf(a0.x, b0.x, s); s = fmaf(a0.y, b0.y, s);
      s = fmaf(a0.z, b0.z, s); s = fmaf(a0.w, b0.w, s);
      s = fmaf(a1.x, b1.x, s); s = fmaf(a1.y, b1.y, s);
      s = fmaf(a1.z, b1.z, s); s = fmaf(a1.w, b1.w, s);
      acc[j] = s;
    }
#pragma unroll
    for (int j = 0; j < KSEL; ++j) {
#pragma unroll
      for (int off = 32; off; off >>= 1)
        acc[j] += __shfl_xor(acc[j], off);
    }
    float v = acc[0];
#pragma unroll
    for (int j = 1; j < KSEL; ++j) if (lane == j) v = acc[j];
    if (lane < KSEL)
      vals[(size_t)(ent >> 4) * (KSEL * KSEL) + (ent & 15) * KSEL + lane]
          = v * sfac[lane];

    ent = nent; a0 = na0; a1 = na1;
  }
}

// ---------------------------------------------------------------------------
// Kernel 4: one block per output row. Zero a 40 KB LDS row, scatter the 100
// values at topk[row][slot]*10+j, stream the row out as coalesced NT float4.
// Zeros + values fused into ONE dense 164 MB write pass.
// ---------------------------------------------------------------------------
__global__ __launch_bounds__(256) void k_out(
    const int* __restrict__ topk, const float* __restrict__ vals,
    float* __restrict__ out)
{
  __shared__ float srow[NCLASSES];   // 40 KB

  const int row = blockIdx.x;
  const int tid = threadIdx.x;

  f32x4* s4 = reinterpret_cast<f32x4*>(srow);
#pragma unroll
  for (int i = 0; i < 10; ++i) {
    const int idx = tid + i * 256;
    if (idx < NCLASSES / 4) s4[idx] = (f32x4)0.f;
  }
  __syncthreads();

  if (tid < KSEL * KSEL) {
    const int kk = tid / KSEL, j = tid % KSEL;
    const int col = topk[(size_t)row * KSEL + kk] * KSEL + j;
    srow[col] = vals[(size_t)row * (KSEL * KSEL) + tid];
  }
  __syncthreads();

  f32x4* orow = reinterpret_cast<f32x4*>(out + (size_t)row * NCLASSES);
#pragma unroll
  for (int i = 0; i < 10; ++i) {
    const int idx = tid + i * 256;
    if (idx < NCLASSES / 4)
      __builtin_nontemporal_store(s4[idx], orow + idx);
  }
}

// ---------------------------------------------------------------------------
extern "C" void kernel_launch(void* const* d_in, const int* in_sizes, int n_in,
                              void* d_out, int out_size, void* d_ws, size_t ws_size,
                              hipStream_t stream) {
  const float* img    = (const float*)d_in[0];
  const float* proto  = (const float*)d_in[1];
  const float* text   = (const float*)d_in[2];
  const float* lscale = (const float*)d_in[3];

  unsigned short* prob = (unsigned short*)d_out;   // scratch, overwritten by k_out
  float* out = (float*)d_out;

  // ws layout (~2.8 MB): counts @0, buckets @4K, topk @1.03M, vals @1.2M
  int*   counts  = (int*)d_ws;                            // 4 KB
  int*   buckets = (int*)((char*)d_ws + 4096);            // 1,024,000 B
  int*   topk    = (int*)((char*)d_ws + 4096 + 1024000);  // 163,840 B
  float* vals    = (float*)((char*)d_ws + 4096 + 1024000 + 163840); // 1.6 MB

  k_gemm<<<dim3(B_ROWS / GBM, 1024 / GBN), 256, 0, stream>>>(
      img, proto, prob, counts);
  k_select<<<B_ROWS / 4, 256, 0, stream>>>(
      prob, img, proto, counts, buckets, topk);
  k_compute<<<NPROTO, 256, 0, stream>>>(
      img, text, counts, buckets, lscale, vals);
  k_out<<<B_ROWS, 256, 0, stream>>>(topk, vals, out);
}

// Round 16
// 103.272 us; speedup vs baseline: 1.1000x; 1.1000x over previous
//
#include <hip/hip_runtime.h>
#include <cfloat>
#include <math.h>

// Problem constants (fixed by the reference)
#define B_ROWS   4096
#define DIM      512
#define NPROTO   1000
#define NCLASSES 10000
#define KSEL     10
#define KCAND    12                // approx candidates rescored in f32
#define CAP      256               // bucket capacity (avg 41)
#define PROB_LD  1024

// d_out layout: prob f16 4096x1024 at [0, PROB_BYTES). k_select self-zeroes
// each prob row after consuming it; zhi = [PROB_BYTES, OUT) is zeroed in
// shares by k_gemm (post-loop) and k_select, always POST-compute NT stores
// with no barrier after (R6 lesson: barrier forces vmcnt(0) drain).
// R12-R15 all measured WORSE than this zero strategy -- do not revisit.
#define PROB_BYTES 8388608u
#define OUT_BYTES  163840000u
#define ZHI_N4     ((OUT_BYTES - PROB_BYTES) / 16)   // 9715712 f32x4
#define ZQ1        6000000u                          // 96 MB zeroed by gemm
#define ZS1        0u
#define ZQ2        (ZHI_N4 - ZQ1)                    // ~59.5 MB by select
#define ZS2        ZQ1

// MFMA GEMM tiling: 128x128 tile, 512 threads / 8 waves (R16 change --
// halves proto re-fetch vs R10's 64x128 and doubles MFMA per barrier).
#define GBM 128
#define GBN 128
#define GBK 32
#define ALD 40                     // padded LDS row stride (bf16 elems)

typedef short s16x8 __attribute__((ext_vector_type(8)));
typedef float f32x4 __attribute__((ext_vector_type(4)));

static __device__ __forceinline__ unsigned short f2bf(float f) {
  unsigned int x = __float_as_uint(f);
  return (unsigned short)((x + 0x7fffu + ((x >> 16) & 1u)) >> 16);  // RNE
}
static __device__ __forceinline__ s16x8 cvt8(float4 a, float4 b) {
  s16x8 r;
  r[0]=f2bf(a.x); r[1]=f2bf(a.y); r[2]=f2bf(a.z); r[3]=f2bf(a.w);
  r[4]=f2bf(b.x); r[5]=f2bf(b.y); r[6]=f2bf(b.z); r[7]=f2bf(b.w);
  return r;
}
static __device__ __forceinline__ unsigned short f2h(float f) {
  _Float16 h = (_Float16)f;
  return __builtin_bit_cast(unsigned short, h);
}
// monotone map: IEEE f16 bits -> u16 preserving order (no NaNs here)
static __device__ __forceinline__ unsigned mono16(unsigned h) {
  return (h & 0x8000u) ? (~h & 0xffffu) : (h | 0x8000u);
}

static __device__ __forceinline__ void zero_share(
    f32x4* __restrict__ z, unsigned start, unsigned count,
    unsigned gth, unsigned nthreads)
{
  const f32x4 z4 = (f32x4)0.f;
  for (unsigned i = start + gth; i < start + count; i += nthreads)
    __builtin_nontemporal_store(z4, z + i);
}

// ---------------------------------------------------------------------------
// Kernel 1: prob(f16) = bf16(img) @ bf16(proto).T via 16x16x32 MFMA.
// 128x128 tile, 512 threads = 8 waves in a 4x2 grid; each wave computes a
// 32x64 sub-tile (2x4 fragments) -- identical per-wave shape to the R10
// kernel, just twice as many waves per block and half the grid. f32->bf16
// inline at the LDS-store site. Block (0,0) zeroes counts; every block
// writes its zhi zero share post-loop (async drain, no barrier after).
// ---------------------------------------------------------------------------
__global__ __launch_bounds__(512) void k_gemm(
    const float* __restrict__ img, const float* __restrict__ proto,
    unsigned short* __restrict__ prob, f32x4* __restrict__ outz,
    int* __restrict__ counts)
{
  __shared__ short Al[GBM * ALD];   // 10 KB
  __shared__ short Bl[GBN * ALD];   // 10 KB

  const int tid  = threadIdx.x;
  const int lane = tid & 63, wave = tid >> 6;       // 8 waves
  const int wr = wave >> 1, wc = wave & 1;          // 4x2 wave grid
  const int row0 = blockIdx.x * GBM;
  const int col0 = blockIdx.y * GBN;
  const unsigned gth = (blockIdx.y * gridDim.x + blockIdx.x) * 512 + tid;

  const int sr = tid >> 2;          // staging row 0..127
  const int sc = (tid & 3) * 8;     // staging k-col 0,8,16,24

  int pa = col0 + sr; if (pa > NPROTO - 1) pa = NPROTO - 1;
  const float* gA = img   + (size_t)(row0 + sr) * DIM + sc;
  const float* gB = proto + (size_t)pa * DIM + sc;

  float4 ra0 = *(const float4*)(gA), ra1 = *(const float4*)(gA + 4);
  float4 rb0 = *(const float4*)(gB), rb1 = *(const float4*)(gB + 4);

  f32x4 acc[2][4];
#pragma unroll
  for (int m = 0; m < 2; ++m)
#pragma unroll
    for (int n = 0; n < 4; ++n) acc[m][n] = (f32x4)0.f;

  const int kg = lane >> 4;   // k-group 0..3
  const int fr = lane & 15;   // fragment row/col

  for (int kt = 0; kt < DIM / GBK; ++kt) {
    *(s16x8*)&Al[sr * ALD + sc] = cvt8(ra0, ra1);
    *(s16x8*)&Bl[sr * ALD + sc] = cvt8(rb0, rb1);
    __syncthreads();

    if (kt + 1 < DIM / GBK) {
      const int k0 = (kt + 1) * GBK;
      ra0 = *(const float4*)(gA + k0);  ra1 = *(const float4*)(gA + k0 + 4);
      rb0 = *(const float4*)(gB + k0);  rb1 = *(const float4*)(gB + k0 + 4);
    }

    s16x8 af[2], bf[4];
#pragma unroll
    for (int m = 0; m < 2; ++m)
      af[m] = *(const s16x8*)&Al[(wr * 32 + m * 16 + fr) * ALD + kg * 8];
#pragma unroll
    for (int n = 0; n < 4; ++n)
      bf[n] = *(const s16x8*)&Bl[(wc * 64 + n * 16 + fr) * ALD + kg * 8];
#pragma unroll
    for (int m = 0; m < 2; ++m)
#pragma unroll
      for (int n = 0; n < 4; ++n)
        acc[m][n] = __builtin_amdgcn_mfma_f32_16x16x32_bf16(
            af[m], bf[n], acc[m][n], 0, 0, 0);
    __syncthreads();
  }

  // epilogue: C/D layout (m89/m91): col = lane&15, row = (lane>>4)*4 + reg
#pragma unroll
  for (int m = 0; m < 2; ++m)
#pragma unroll
    for (int n = 0; n < 4; ++n) {
      const int r = row0 + wr * 32 + m * 16 + (lane >> 4) * 4;
      const int c = col0 + wc * 64 + n * 16 + fr;
#pragma unroll
      for (int reg = 0; reg < 4; ++reg)
        prob[(size_t)(r + reg) * PROB_LD + c] = f2h(acc[m][n][reg]);
    }

  if (blockIdx.x == 0 && blockIdx.y == 0)
    for (int i = tid; i < NPROTO; i += 512) counts[i] = 0;

  // post-loop zero share: no barrier after -> fully async drain
  zero_share(outz, ZS1, ZQ1, gth, 256 * 512);
}

// ---------------------------------------------------------------------------
// Kernel 2: fused top-12 -> f32 rescore -> top-10 pick -> bucket build.
// One wave per row, register-packed argmax (R10-verbatim, proven).
// ---------------------------------------------------------------------------
__global__ __launch_bounds__(256) void k_select(
    unsigned short* __restrict__ prob, const float* __restrict__ img,
    const float* __restrict__ proto, int* __restrict__ counts,
    int* __restrict__ buckets, f32x4* __restrict__ outz)
{
  const int tid  = threadIdx.x;
  const int wave = tid >> 6, lane = tid & 63;
  const int row  = blockIdx.x * 4 + wave;

  // lane l owns u32 words l*8 .. l*8+7 of the row = cols l*16 .. l*16+15
  unsigned cand[16];
  {
    const uint4* pu = reinterpret_cast<const uint4*>(
        prob + (size_t)row * PROB_LD) + lane * 2;
    const uint4 w0 = pu[0], w1 = pu[1];
    const unsigned w[8] = {w0.x, w0.y, w0.z, w0.w, w1.x, w1.y, w1.z, w1.w};
    const int cbase = lane * 16;
#pragma unroll
    for (int r = 0; r < 8; ++r) {
      const int c0 = cbase + r * 2;
      const unsigned lo = w[r] & 0xffffu, hi = w[r] >> 16;
      cand[r * 2]     = (c0     < NPROTO) ? ((mono16(lo) << 16) | (0xffffu - c0))       : 0u;
      cand[r * 2 + 1] = (c0 + 1 < NPROTO) ? ((mono16(hi) << 16) | (0xffffu - (c0 + 1))) : 0u;
    }
  }

  // 12 rounds of pure-VALU wave argmax
  int ci[KCAND];
#pragma unroll
  for (int kk = 0; kk < KCAND; ++kk) {
    unsigned best = cand[0];
#pragma unroll
    for (int r = 1; r < 16; ++r) best = max(best, cand[r]);
#pragma unroll
    for (int off = 32; off; off >>= 1)
      best = max(best, (unsigned)__shfl_xor((int)best, off));
    ci[kk] = 0xffff - (int)(best & 0xffffu);
#pragma unroll
    for (int r = 0; r < 16; ++r)
      if (cand[r] == best) cand[r] = 0u;
  }

  // self-zero the consumed f16 prob row (2 KB = 128 f32x4)
  {
    const f32x4 z4 = (f32x4)0.f;
    f32x4* prow = reinterpret_cast<f32x4*>(prob + (size_t)row * PROB_LD);
    __builtin_nontemporal_store(z4, prow + lane);
    __builtin_nontemporal_store(z4, prow + 64 + lane);
  }

  // exact f32 rescore of the 12 candidates
  const float4* a4 = reinterpret_cast<const float4*>(img + (size_t)row * DIM);
  const float4 a0 = a4[lane], a1 = a4[64 + lane];
  float dv[KCAND];
#pragma unroll
  for (int j = 0; j < KCAND; ++j) {
    const float4* p4 = reinterpret_cast<const float4*>(proto + (size_t)ci[j] * DIM);
    const float4 b0 = p4[lane], b1 = p4[64 + lane];
    float s = 0.f;
    s = fmaf(a0.x, b0.x, s); s = fmaf(a0.y, b0.y, s);
    s = fmaf(a0.z, b0.z, s); s = fmaf(a0.w, b0.w, s);
    s = fmaf(a1.x, b1.x, s); s = fmaf(a1.y, b1.y, s);
    s = fmaf(a1.z, b1.z, s); s = fmaf(a1.w, b1.w, s);
#pragma unroll
    for (int off = 32; off; off >>= 1) s += __shfl_xor(s, off);
    dv[j] = s;
  }

  // top-10 pick (uniform across lanes) + bucket build (lane kk does pick kk)
  unsigned picked = 0;
  for (int kk = 0; kk < KSEL; ++kk) {
    float bv = -FLT_MAX;
    int   bj = 0;
#pragma unroll
    for (int j = 0; j < KCAND; ++j)
      if (!((picked >> j) & 1u) && dv[j] > bv) { bv = dv[j]; bj = j; }
    picked |= 1u << bj;
    if (lane == kk) {
      const int pp  = ci[bj];
      const int pos = atomicAdd(&counts[pp], 1);
      if (pos < CAP) buckets[pp * CAP + pos] = row;
    }
  }

  zero_share(outz, ZS2, ZQ2, blockIdx.x * 256 + tid, 1024 * 256);
}

// ---------------------------------------------------------------------------
// Kernel 3: one block per proto; stage its 10 raw text rows in LDS + inverse
// norms (scale folded into dot epilogue); prefetched bucketed-row loop.
// (R10-verbatim.)
// ---------------------------------------------------------------------------
__global__ __launch_bounds__(256) void k_compute(
    const float* __restrict__ img, const float* __restrict__ text,
    const int* __restrict__ counts, const int* __restrict__ buckets,
    const float* __restrict__ logit_scale, float* __restrict__ out)
{
  __shared__ float stext[KSEL * DIM];   // 20 KB (raw)
  __shared__ float sfac[KSEL];

  const int p    = blockIdx.x;
  const int tid  = threadIdx.x;
  const int wave = tid >> 6, lane = tid & 63;

  {
    const float4* src = reinterpret_cast<const float4*>(text + (size_t)p * KSEL * DIM);
    float4* dst = reinterpret_cast<float4*>(stext);
#pragma unroll
    for (int i = 0; i < 5; ++i) dst[tid + i * 256] = src[tid + i * 256];
  }
  __syncthreads();

  const float scale = expf(logit_scale[0]);
#pragma unroll
  for (int j = wave; j < KSEL; j += 4) {
    const float4* t4 = reinterpret_cast<const float4*>(stext + j * DIM);
    float4 v0 = t4[lane], v1 = t4[64 + lane];
    float s = 0.f;
    s = fmaf(v0.x, v0.x, s); s = fmaf(v0.y, v0.y, s);
    s = fmaf(v0.z, v0.z, s); s = fmaf(v0.w, v0.w, s);
    s = fmaf(v1.x, v1.x, s); s = fmaf(v1.y, v1.y, s);
    s = fmaf(v1.z, v1.z, s); s = fmaf(v1.w, v1.w, s);
#pragma unroll
    for (int off = 32; off; off >>= 1) s += __shfl_down(s, off);
    if (lane == 0) sfac[j] = scale / sqrtf(s);
  }
  __syncthreads();

  const int n = min(counts[p], CAP);
  const float4* st4 = reinterpret_cast<const float4*>(stext);
  const int* bkt = buckets + p * CAP;

  int row = -1, nrow;
  float4 a0, a1, na0, na1;
  if (wave < n) {
    row = bkt[wave];
    const float4* a4 = reinterpret_cast<const float4*>(img + (size_t)row * DIM);
    a0 = a4[lane]; a1 = a4[64 + lane];
  }

  for (int i = wave; i < n; i += 4) {
    const int inext = i + 4;
    if (inext < n) {
      nrow = bkt[inext];
      const float4* a4 = reinterpret_cast<const float4*>(img + (size_t)nrow * DIM);
      na0 = a4[lane]; na1 = a4[64 + lane];
    }

    float acc[KSEL];
#pragma unroll
    for (int j = 0; j < KSEL; ++j) {
      const float4 b0 = st4[j * 128 + lane];
      const float4 b1 = st4[j * 128 + 64 + lane];
      float s = 0.f;
      s = fmaf(a0.x, b0.x, s); s = fmaf(a0.y, b0.y, s);
      s = fmaf(a0.z, b0.z, s); s = fmaf(a0.w, b0.w, s);
      s = fmaf(a1.x, b1.x, s); s = fmaf(a1.y, b1.y, s);
      s = fmaf(a1.z, b1.z, s); s = fmaf(a1.w, b1.w, s);
      acc[j] = s;
    }
#pragma unroll
    for (int j = 0; j < KSEL; ++j) {
#pragma unroll
      for (int off = 32; off; off >>= 1)
        acc[j] += __shfl_xor(acc[j], off);
    }
    float v = acc[0];
#pragma unroll
    for (int j = 1; j < KSEL; ++j) if (lane == j) v = acc[j];
    if (lane < KSEL)
      out[(size_t)row * NCLASSES + p * KSEL + lane] = v * sfac[lane];

    row = nrow; a0 = na0; a1 = na1;
  }
}

// ---------------------------------------------------------------------------
extern "C" void kernel_launch(void* const* d_in, const int* in_sizes, int n_in,
                              void* d_out, int out_size, void* d_ws, size_t ws_size,
                              hipStream_t stream) {
  const float* img    = (const float*)d_in[0];
  const float* proto  = (const float*)d_in[1];
  const float* text   = (const float*)d_in[2];
  const float* lscale = (const float*)d_in[3];

  unsigned short* prob = (unsigned short*)d_out;
  f32x4*  outz = (f32x4*)((char*)d_out + PROB_BYTES);
  float*  out  = (float*)d_out;

  // ws layout (~1.03 MB)
  int* counts  = (int*)d_ws;                      // 1000*4 (pad to 4096)
  int* buckets = (int*)((char*)d_ws + 4096);      // 1000*256*4

  k_gemm<<<dim3(B_ROWS / GBM, 1024 / GBN), 512, 0, stream>>>(
      img, proto, prob, outz, counts);
  k_select<<<B_ROWS / 4, 256, 0, stream>>>(prob, img, proto, counts, buckets, outz);
  k_compute<<<NPROTO, 256, 0, stream>>>(img, text, counts, buckets, lscale, out);
}

// Round 17
// 100.111 us; speedup vs baseline: 1.1348x; 1.0316x over previous
//
#include <hip/hip_runtime.h>
#include <cfloat>
#include <math.h>

// Problem constants (fixed by the reference)
#define B_ROWS   4096
#define DIM      512
#define NPROTO   1000
#define NCLASSES 10000
#define KSEL     10
#define KCAND    12                // approx candidates rescored in f32
#define CAP      256               // bucket capacity (avg 41)
#define PROB_LD  1024

// d_out layout: prob f16 4096x1024 at [0, PROB_BYTES). k_select self-zeroes
// each prob row after consuming it; zhi = [PROB_BYTES, OUT) is zeroed in
// shares by k_gemm (post-loop) and k_select, always POST-compute NT stores
// with no barrier after (R6 lesson). R12-R16 alternatives all measured
// worse than this layout -- do not revisit.
#define PROB_BYTES 8388608u
#define OUT_BYTES  163840000u
#define ZHI_N4     ((OUT_BYTES - PROB_BYTES) / 16)   // 9715712 f32x4
#define ZQ1        6000000u                          // 96 MB zeroed by gemm
#define ZS1        0u
#define ZQ2        (ZHI_N4 - ZQ1)                    // ~59.5 MB by select
#define ZS2        ZQ1

// MFMA GEMM tiling (R10-verified structure)
#define GBM 64
#define GBN 128
#define GBK 32
#define ALD 40                     // padded LDS row stride (bf16 elems)

typedef short s16x8 __attribute__((ext_vector_type(8)));
typedef float f32x4 __attribute__((ext_vector_type(4)));

static __device__ __forceinline__ unsigned short f2bf(float f) {
  unsigned int x = __float_as_uint(f);
  return (unsigned short)((x + 0x7fffu + ((x >> 16) & 1u)) >> 16);  // RNE
}
static __device__ __forceinline__ s16x8 cvt8(float4 a, float4 b) {
  s16x8 r;
  r[0]=f2bf(a.x); r[1]=f2bf(a.y); r[2]=f2bf(a.z); r[3]=f2bf(a.w);
  r[4]=f2bf(b.x); r[5]=f2bf(b.y); r[6]=f2bf(b.z); r[7]=f2bf(b.w);
  return r;
}
static __device__ __forceinline__ unsigned short f2h(float f) {
  _Float16 h = (_Float16)f;
  return __builtin_bit_cast(unsigned short, h);
}
// monotone map: IEEE f16 bits -> u16 preserving order (no NaNs here)
static __device__ __forceinline__ unsigned mono16(unsigned h) {
  return (h & 0x8000u) ? (~h & 0xffffu) : (h | 0x8000u);
}

static __device__ __forceinline__ void zero_share(
    f32x4* __restrict__ z, unsigned start, unsigned count,
    unsigned gth, unsigned nthreads)
{
  const f32x4 z4 = (f32x4)0.f;
  for (unsigned i = start + gth; i < start + count; i += nthreads)
    __builtin_nontemporal_store(z4, z + i);
}

// ---------------------------------------------------------------------------
// Kernel 1: prob(f16) = bf16(img) @ bf16(proto).T via 16x16x32 MFMA,
// f32->bf16 inline at the LDS-store site (R10-verbatim). Block (0,0) zeroes
// counts; every block writes its zhi zero share post-loop (async drain).
// ---------------------------------------------------------------------------
__global__ __launch_bounds__(256) void k_gemm(
    const float* __restrict__ img, const float* __restrict__ proto,
    unsigned short* __restrict__ prob, f32x4* __restrict__ outz,
    int* __restrict__ counts)
{
  __shared__ short Al[GBM * ALD];   // 5 KB
  __shared__ short Bl[GBN * ALD];   // 10 KB

  const int tid  = threadIdx.x;
  const int lane = tid & 63, wave = tid >> 6;
  const int wr = wave >> 1, wc = wave & 1;
  const int row0 = blockIdx.x * GBM;
  const int col0 = blockIdx.y * GBN;
  const unsigned gth = (blockIdx.y * gridDim.x + blockIdx.x) * 256 + tid;

  const int sr = tid >> 2;          // staging row 0..63
  const int sc = (tid & 3) * 8;     // staging k-col 0,8,16,24

  int pa = col0 + sr;      if (pa > NPROTO - 1) pa = NPROTO - 1;
  int pb = col0 + 64 + sr; if (pb > NPROTO - 1) pb = NPROTO - 1;
  const float* gA  = img   + (size_t)(row0 + sr) * DIM + sc;
  const float* gB0 = proto + (size_t)pa * DIM + sc;
  const float* gB1 = proto + (size_t)pb * DIM + sc;

  float4 ra0  = *(const float4*)(gA);      float4 ra1  = *(const float4*)(gA + 4);
  float4 rb00 = *(const float4*)(gB0);     float4 rb01 = *(const float4*)(gB0 + 4);
  float4 rb10 = *(const float4*)(gB1);     float4 rb11 = *(const float4*)(gB1 + 4);

  f32x4 acc[2][4];
#pragma unroll
  for (int m = 0; m < 2; ++m)
#pragma unroll
    for (int n = 0; n < 4; ++n) acc[m][n] = (f32x4)0.f;

  const int kg = lane >> 4;   // k-group 0..3
  const int fr = lane & 15;   // fragment row/col

  for (int kt = 0; kt < DIM / GBK; ++kt) {
    *(s16x8*)&Al[sr * ALD + sc]        = cvt8(ra0, ra1);
    *(s16x8*)&Bl[sr * ALD + sc]        = cvt8(rb00, rb01);
    *(s16x8*)&Bl[(64 + sr) * ALD + sc] = cvt8(rb10, rb11);
    __syncthreads();

    if (kt + 1 < DIM / GBK) {
      const int k0 = (kt + 1) * GBK;
      ra0  = *(const float4*)(gA + k0);   ra1  = *(const float4*)(gA + k0 + 4);
      rb00 = *(const float4*)(gB0 + k0);  rb01 = *(const float4*)(gB0 + k0 + 4);
      rb10 = *(const float4*)(gB1 + k0);  rb11 = *(const float4*)(gB1 + k0 + 4);
    }

    s16x8 af[2], bf[4];
#pragma unroll
    for (int m = 0; m < 2; ++m)
      af[m] = *(const s16x8*)&Al[(wr * 32 + m * 16 + fr) * ALD + kg * 8];
#pragma unroll
    for (int n = 0; n < 4; ++n)
      bf[n] = *(const s16x8*)&Bl[(wc * 64 + n * 16 + fr) * ALD + kg * 8];
#pragma unroll
    for (int m = 0; m < 2; ++m)
#pragma unroll
      for (int n = 0; n < 4; ++n)
        acc[m][n] = __builtin_amdgcn_mfma_f32_16x16x32_bf16(
            af[m], bf[n], acc[m][n], 0, 0, 0);
    __syncthreads();
  }

  // epilogue: C/D layout (m89/m91): col = lane&15, row = (lane>>4)*4 + reg
#pragma unroll
  for (int m = 0; m < 2; ++m)
#pragma unroll
    for (int n = 0; n < 4; ++n) {
      const int r = row0 + wr * 32 + m * 16 + (lane >> 4) * 4;
      const int c = col0 + wc * 64 + n * 16 + fr;
#pragma unroll
      for (int reg = 0; reg < 4; ++reg)
        prob[(size_t)(r + reg) * PROB_LD + c] = f2h(acc[m][n][reg]);
    }

  if (blockIdx.x == 0 && blockIdx.y == 0)
    for (int i = tid; i < NPROTO; i += 256) counts[i] = 0;

  // post-loop zero share: no barrier after -> fully async drain
  zero_share(outz, ZS1, ZQ1, gth, 512 * 256);
}

// ---------------------------------------------------------------------------
// Kernel 2: fused top-12 -> f32 rescore -> top-10 pick -> bucket build.
// One wave per row, register-packed argmax (R10-verbatim, proven).
// ---------------------------------------------------------------------------
__global__ __launch_bounds__(256) void k_select(
    unsigned short* __restrict__ prob, const float* __restrict__ img,
    const float* __restrict__ proto, int* __restrict__ counts,
    int* __restrict__ buckets, f32x4* __restrict__ outz)
{
  const int tid  = threadIdx.x;
  const int wave = tid >> 6, lane = tid & 63;
  const int row  = blockIdx.x * 4 + wave;

  // lane l owns u32 words l*8 .. l*8+7 of the row = cols l*16 .. l*16+15
  unsigned cand[16];
  {
    const uint4* pu = reinterpret_cast<const uint4*>(
        prob + (size_t)row * PROB_LD) + lane * 2;
    const uint4 w0 = pu[0], w1 = pu[1];
    const unsigned w[8] = {w0.x, w0.y, w0.z, w0.w, w1.x, w1.y, w1.z, w1.w};
    const int cbase = lane * 16;
#pragma unroll
    for (int r = 0; r < 8; ++r) {
      const int c0 = cbase + r * 2;
      const unsigned lo = w[r] & 0xffffu, hi = w[r] >> 16;
      cand[r * 2]     = (c0     < NPROTO) ? ((mono16(lo) << 16) | (0xffffu - c0))       : 0u;
      cand[r * 2 + 1] = (c0 + 1 < NPROTO) ? ((mono16(hi) << 16) | (0xffffu - (c0 + 1))) : 0u;
    }
  }

  // 12 rounds of pure-VALU wave argmax
  int ci[KCAND];
#pragma unroll
  for (int kk = 0; kk < KCAND; ++kk) {
    unsigned best = cand[0];
#pragma unroll
    for (int r = 1; r < 16; ++r) best = max(best, cand[r]);
#pragma unroll
    for (int off = 32; off; off >>= 1)
      best = max(best, (unsigned)__shfl_xor((int)best, off));
    ci[kk] = 0xffff - (int)(best & 0xffffu);
#pragma unroll
    for (int r = 0; r < 16; ++r)
      if (cand[r] == best) cand[r] = 0u;
  }

  // self-zero the consumed f16 prob row (2 KB = 128 f32x4)
  {
    const f32x4 z4 = (f32x4)0.f;
    f32x4* prow = reinterpret_cast<f32x4*>(prob + (size_t)row * PROB_LD);
    __builtin_nontemporal_store(z4, prow + lane);
    __builtin_nontemporal_store(z4, prow + 64 + lane);
  }

  // exact f32 rescore of the 12 candidates
  const float4* a4 = reinterpret_cast<const float4*>(img + (size_t)row * DIM);
  const float4 a0 = a4[lane], a1 = a4[64 + lane];
  float dv[KCAND];
#pragma unroll
  for (int j = 0; j < KCAND; ++j) {
    const float4* p4 = reinterpret_cast<const float4*>(proto + (size_t)ci[j] * DIM);
    const float4 b0 = p4[lane], b1 = p4[64 + lane];
    float s = 0.f;
    s = fmaf(a0.x, b0.x, s); s = fmaf(a0.y, b0.y, s);
    s = fmaf(a0.z, b0.z, s); s = fmaf(a0.w, b0.w, s);
    s = fmaf(a1.x, b1.x, s); s = fmaf(a1.y, b1.y, s);
    s = fmaf(a1.z, b1.z, s); s = fmaf(a1.w, b1.w, s);
#pragma unroll
    for (int off = 32; off; off >>= 1) s += __shfl_xor(s, off);
    dv[j] = s;
  }

  // top-10 pick (uniform across lanes) + bucket build (lane kk does pick kk)
  unsigned picked = 0;
  for (int kk = 0; kk < KSEL; ++kk) {
    float bv = -FLT_MAX;
    int   bj = 0;
#pragma unroll
    for (int j = 0; j < KCAND; ++j)
      if (!((picked >> j) & 1u) && dv[j] > bv) { bv = dv[j]; bj = j; }
    picked |= 1u << bj;
    if (lane == kk) {
      const int pp  = ci[bj];
      const int pos = atomicAdd(&counts[pp], 1);
      if (pos < CAP) buckets[pp * CAP + pos] = row;
    }
  }

  zero_share(outz, ZS2, ZQ2, blockIdx.x * 256 + tid, 1024 * 256);
}

// ---------------------------------------------------------------------------
// Kernel 3: one block per proto, now 512 threads / 8 waves (R17 change --
// halves staging trips, halves row-loop rounds per wave, halves the Poisson-
// tail exposure). Stage 10 raw text rows in LDS + inverse norms (scale folded
// into dot epilogue); prefetched bucketed-row loop.
// ---------------------------------------------------------------------------
__global__ __launch_bounds__(512) void k_compute(
    const float* __restrict__ img, const float* __restrict__ text,
    const int* __restrict__ counts, const int* __restrict__ buckets,
    const float* __restrict__ logit_scale, float* __restrict__ out)
{
  __shared__ float stext[KSEL * DIM];   // 20 KB (raw)
  __shared__ float sfac[KSEL];

  const int p    = blockIdx.x;
  const int tid  = threadIdx.x;
  const int wave = tid >> 6, lane = tid & 63;   // 8 waves

  {
    const float4* src = reinterpret_cast<const float4*>(text + (size_t)p * KSEL * DIM);
    float4* dst = reinterpret_cast<float4*>(stext);
#pragma unroll
    for (int i = 0; i < 3; ++i) {
      const int idx = tid + i * 512;
      if (idx < KSEL * DIM / 4) dst[idx] = src[idx];
    }
  }
  __syncthreads();

  const float scale = expf(logit_scale[0]);
#pragma unroll
  for (int j = wave; j < KSEL; j += 8) {
    const float4* t4 = reinterpret_cast<const float4*>(stext + j * DIM);
    float4 v0 = t4[lane], v1 = t4[64 + lane];
    float s = 0.f;
    s = fmaf(v0.x, v0.x, s); s = fmaf(v0.y, v0.y, s);
    s = fmaf(v0.z, v0.z, s); s = fmaf(v0.w, v0.w, s);
    s = fmaf(v1.x, v1.x, s); s = fmaf(v1.y, v1.y, s);
    s = fmaf(v1.z, v1.z, s); s = fmaf(v1.w, v1.w, s);
#pragma unroll
    for (int off = 32; off; off >>= 1) s += __shfl_down(s, off);
    if (lane == 0) sfac[j] = scale / sqrtf(s);
  }
  __syncthreads();

  const int n = min(counts[p], CAP);
  const float4* st4 = reinterpret_cast<const float4*>(stext);
  const int* bkt = buckets + p * CAP;

  int row = -1, nrow;
  float4 a0, a1, na0, na1;
  if (wave < n) {
    row = bkt[wave];
    const float4* a4 = reinterpret_cast<const float4*>(img + (size_t)row * DIM);
    a0 = a4[lane]; a1 = a4[64 + lane];
  }

  for (int i = wave; i < n; i += 8) {
    const int inext = i + 8;
    if (inext < n) {
      nrow = bkt[inext];
      const float4* a4 = reinterpret_cast<const float4*>(img + (size_t)nrow * DIM);
      na0 = a4[lane]; na1 = a4[64 + lane];
    }

    float acc[KSEL];
#pragma unroll
    for (int j = 0; j < KSEL; ++j) {
      const float4 b0 = st4[j * 128 + lane];
      const float4 b1 = st4[j * 128 + 64 + lane];
      float s = 0.f;
      s = fmaf(a0.x, b0.x, s); s = fmaf(a0.y, b0.y, s);
      s = fmaf(a0.z, b0.z, s); s = fmaf(a0.w, b0.w, s);
      s = fmaf(a1.x, b1.x, s); s = fmaf(a1.y, b1.y, s);
      s = fmaf(a1.z, b1.z, s); s = fmaf(a1.w, b1.w, s);
      acc[j] = s;
    }
#pragma unroll
    for (int j = 0; j < KSEL; ++j) {
#pragma unroll
      for (int off = 32; off; off >>= 1)
        acc[j] += __shfl_xor(acc[j], off);
    }
    float v = acc[0];
#pragma unroll
    for (int j = 1; j < KSEL; ++j) if (lane == j) v = acc[j];
    if (lane < KSEL)
      out[(size_t)row * NCLASSES + p * KSEL + lane] = v * sfac[lane];

    row = nrow; a0 = na0; a1 = na1;
  }
}

// ---------------------------------------------------------------------------
extern "C" void kernel_launch(void* const* d_in, const int* in_sizes, int n_in,
                              void* d_out, int out_size, void* d_ws, size_t ws_size,
                              hipStream_t stream) {
  const float* img    = (const float*)d_in[0];
  const float* proto  = (const float*)d_in[1];
  const float* text   = (const float*)d_in[2];
  const float* lscale = (const float*)d_in[3];

  unsigned short* prob = (unsigned short*)d_out;
  f32x4*  outz = (f32x4*)((char*)d_out + PROB_BYTES);
  float*  out  = (float*)d_out;

  // ws layout (~1.03 MB)
  int* counts  = (int*)d_ws;                      // 1000*4 (pad to 4096)
  int* buckets = (int*)((char*)d_ws + 4096);      // 1000*256*4

  k_gemm<<<dim3(B_ROWS / GBM, 1024 / GBN), 256, 0, stream>>>(
      img, proto, prob, outz, counts);
  k_select<<<B_ROWS / 4, 256, 0, stream>>>(prob, img, proto, counts, buckets, outz);
  k_compute<<<NPROTO, 512, 0, stream>>>(img, text, counts, buckets, lscale, out);
}